// Round 4
// baseline (331.892 us; speedup 1.0000x reference)
//
#include <hip/hip_runtime.h>

#define BB 16
#define TT 256
#define NN 2048
#define TC 16            // t-chunk per block (2048 blocks -> 8 blocks/CU)
#define NSLICES (BB * (TT / TC))   // 256 non-atomic partial slices
#define NSLICE_ATOMIC 8  // fallback path contention spread
#define WSBASE 16        // scalar slots before per-point arrays

// ws float layout (slice path):
//  [0] recon num  [1] temporal num  [2] num_vel  [3] identity sum  [4] num_visible
//  [WSBASE + (slice*13 + k)*NN + n], slice=b*(TT/TC)+tz, k=0..12:
//      cnt, sp0..2, qp0..2, sg0..2, qg0..2

__device__ __forceinline__ float waveReduceSum(float v) {
#pragma unroll
  for (int o = 32; o > 0; o >>= 1) v += __shfl_down(v, o, 64);
  return v;
}

template <bool USE_ATOMIC>
__global__ __launch_bounds__(256, 8) void stats_kernel(
    const float* __restrict__ pred, const float* __restrict__ gt,
    const float* __restrict__ vis, float* __restrict__ ws) {
  const int n  = blockIdx.x * 256 + threadIdx.x;
  const int b  = blockIdx.y;
  const int tz = blockIdx.z;
  const int t0 = tz * TC;

  const size_t frame0 = (size_t)(b * TT + t0) * NN + n;
  const float3* __restrict__ pp = (const float3*)pred + frame0;
  const float3* __restrict__ gp = (const float3*)gt + frame0;
  const float*  __restrict__ vp = vis + frame0;

  float cnt = 0.f;
  float sp0 = 0, sp1 = 0, sp2 = 0, qp0 = 0, qp1 = 0, qp2 = 0;
  float sg0 = 0, sg1 = 0, sg2 = 0, qg0 = 0, qg1 = 0, qg2 = 0;
  float recon = 0, temporal = 0, nvel = 0;

  // boundary frame t0-1 (velocity only). For t0==0 load frame 0 with mask 0.
  float3 ppv, pgv;
  float mprev;
  {
    const long off = (t0 == 0) ? 0 : -(long)NN;
    ppv = pp[off];
    pgv = gp[off];
    float v = vp[off];
    mprev = (t0 != 0 && v > 0.5f) ? 1.f : 0.f;
  }

#pragma unroll
  for (int i = 0; i < TC; ++i) {
    float3 a = pp[(size_t)i * NN];
    float3 g = gp[(size_t)i * NN];
    float v = vp[(size_t)i * NN];
    float m = (v > 0.5f) ? 1.f : 0.f;

    cnt += m;
    sp0 += m * a.x; sp1 += m * a.y; sp2 += m * a.z;
    qp0 += m * a.x * a.x; qp1 += m * a.y * a.y; qp2 += m * a.z * a.z;
    sg0 += m * g.x; sg1 += m * g.y; sg2 += m * g.z;
    qg0 += m * g.x * g.x; qg1 += m * g.y * g.y; qg2 += m * g.z * g.z;
    float d0 = a.x - g.x, d1 = a.y - g.y, d2 = a.z - g.z;
    recon += m * (d0 * d0 + d1 * d1 + 2.f * d2 * d2);

    float mv = m * mprev;
    float vx = (a.x - ppv.x) - (g.x - pgv.x);
    float vy = (a.y - ppv.y) - (g.y - pgv.y);
    float vz = (a.z - ppv.z) - (g.z - pgv.z);
    temporal += mv * (vx * vx + vy * vy + vz * vz);
    nvel += mv;

    ppv = a; pgv = g; mprev = m;
  }

  float st[13] = {cnt, sp0, sp1, sp2, qp0, qp1, qp2,
                  sg0, sg1, sg2, qg0, qg1, qg2};
  if (USE_ATOMIC) {
    float* pts = ws + WSBASE + (size_t)(b & (NSLICE_ATOMIC - 1)) * 13 * NN;
#pragma unroll
    for (int k = 0; k < 13; ++k) atomicAdd(&pts[k * NN + n], st[k]);
  } else {
    // non-atomic: each (b,tz) owns its own slice
    const int slice = b * (TT / TC) + tz;
    float* pts = ws + WSBASE + (size_t)slice * 13 * NN;
#pragma unroll
    for (int k = 0; k < 13; ++k) pts[k * NN + n] = st[k];
  }

  // global scalars: block reduce, then one atomic per scalar
  __shared__ float sred[3][4];
  float r0 = waveReduceSum(recon);
  float r1 = waveReduceSum(temporal);
  float r2 = waveReduceSum(nvel);
  int lane = threadIdx.x & 63, w = threadIdx.x >> 6;
  if (lane == 0) { sred[0][w] = r0; sred[1][w] = r1; sred[2][w] = r2; }
  __syncthreads();
  if (threadIdx.x < 3) {
    float s = sred[threadIdx.x][0] + sred[threadIdx.x][1] +
              sred[threadIdx.x][2] + sred[threadIdx.x][3];
    atomicAdd(&ws[threadIdx.x], s);
  }
}

template <int NSL>
__global__ __launch_bounds__(256) void identity_kernel(float* __restrict__ ws) {
  const int n = blockIdx.x * 256 + threadIdx.x;
  const float* base = ws + WSBASE;
  float st[13];
#pragma unroll
  for (int k = 0; k < 13; ++k) st[k] = 0.f;
  for (int s = 0; s < NSL; ++s) {
    const float* pts = base + (size_t)s * 13 * NN;
#pragma unroll
    for (int k = 0; k < 13; ++k) st[k] += pts[k * NN + n];
  }
  float c = st[0];
  float sp0 = st[1], sp1 = st[2], sp2 = st[3];
  float qp0 = st[4], qp1 = st[5], qp2 = st[6];
  float sg0 = st[7], sg1 = st[8], sg2 = st[9];
  float qg0 = st[10], qg1 = st[11], qg2 = st[12];

  float inv = 1.f / fmaxf(c, 1.f);        // = 1/c for c>=1; sums are 0 when c==0
  float dv  = 1.f / fmaxf(c - 1.f, 1.f);  // unbiased divisor
  float pv0 = (qp0 - sp0 * sp0 * inv) * dv;
  float pv1 = (qp1 - sp1 * sp1 * inv) * dv;
  float pv2 = (qp2 - sp2 * sp2 * inv) * dv;
  float gv0 = (qg0 - sg0 * sg0 * inv) * dv;
  float gv1 = (qg1 - sg1 * sg1 * inv) * dv;
  float gv2 = (qg2 - sg2 * sg2 * inv) * dv;

  float num = fabsf(pv0 - gv0) + fabsf(pv1 - gv1) + fabsf(pv2 - gv2);
  float den = gv0 + gv1 + gv2 + 1e-6f;
  float contrib = (c > 1.f) ? (num / den) : 0.f;

  __shared__ float sred[2][4];
  float r0 = waveReduceSum(contrib);
  float r1 = waveReduceSum(c);
  int lane = threadIdx.x & 63, w = threadIdx.x >> 6;
  if (lane == 0) { sred[0][w] = r0; sred[1][w] = r1; }
  __syncthreads();
  if (threadIdx.x < 2) {
    float s = sred[threadIdx.x][0] + sred[threadIdx.x][1] +
              sred[threadIdx.x][2] + sred[threadIdx.x][3];
    atomicAdd(&ws[3 + threadIdx.x], s);
  }
}

__global__ void finalize_kernel(const float* __restrict__ ws, float* __restrict__ out) {
  float nv = ws[4];
  float recon = (nv > 0.f) ? ws[0] / fmaxf(nv, 1.f) : 0.f;
  float nvel = ws[2];
  float temporal = (nvel > 0.f) ? ws[1] / fmaxf(nvel, 1.f) : 0.f;
  float identity = ws[3] / (float)NN;

  float rl = recon, tl = temporal, il = identity;
  bool all_pos = (rl > 0.f) && (tl > 0.f) && (il > 0.f);
  float maxc = fmaxf(rl, fmaxf(tl, il));
  float target = maxc / 3.f;
  float thresh = 10.f * target;
  float rw = (all_pos && rl > thresh) ? 1.0f * target / fmaxf(rl, 1e-30f) : 1.0f;
  float tw = (all_pos && tl > thresh) ? 0.5f * target / fmaxf(tl, 1e-30f) : 0.5f;
  float iw = (all_pos && il > thresh) ? 0.1f * target / fmaxf(il, 1e-30f) : 0.1f;

  out[0] = rw * recon + tw * temporal + iw * identity;
  out[1] = recon;
  out[2] = temporal;
  out[3] = identity;
}

extern "C" void kernel_launch(void* const* d_in, const int* in_sizes, int n_in,
                              void* d_out, int out_size, void* d_ws, size_t ws_size,
                              hipStream_t stream) {
  const float* pred = (const float*)d_in[0];
  const float* gt   = (const float*)d_in[1];
  const float* vis  = (const float*)d_in[2];
  float* out = (float*)d_out;
  float* ws  = (float*)d_ws;

  const size_t slice_bytes = (WSBASE + (size_t)NSLICES * 13 * NN) * sizeof(float);
  dim3 g1(NN / 256, BB, TT / TC);

  if (ws_size >= slice_bytes) {
    // non-atomic slice path: only WSBASE scalars need zeroing (slices are
    // fully overwritten by stats_kernel before identity_kernel reads them)
    hipMemsetAsync(d_ws, 0, WSBASE * sizeof(float), stream);
    stats_kernel<false><<<g1, 256, 0, stream>>>(pred, gt, vis, ws);
    identity_kernel<NSLICES><<<dim3(NN / 256), 256, 0, stream>>>(ws);
  } else {
    // fallback: atomic accumulation over NSLICE_ATOMIC slices
    hipMemsetAsync(d_ws, 0,
                   (WSBASE + (size_t)NSLICE_ATOMIC * 13 * NN) * sizeof(float),
                   stream);
    stats_kernel<true><<<g1, 256, 0, stream>>>(pred, gt, vis, ws);
    identity_kernel<NSLICE_ATOMIC><<<dim3(NN / 256), 256, 0, stream>>>(ws);
  }
  finalize_kernel<<<1, 1, 0, stream>>>(ws, out);
}